// Round 1
// baseline (81.774 us; speedup 1.0000x reference)
//
#include <hip/hip_runtime.h>

#define B_ 32
#define N_ 4096
#define M_ 32
#define F_ 256
#define A_ 8

// workspace layout (floats):
//   [0, 256)                      wv  = W @ (a1+a2)
//   [256, 256 + B*A*F)            anchor_feat  (B,A,F)
//   [256 + B*A*F, +B*A)           e2  = anchor_feat @ (a1-a2)
#define WS_WV 0
#define WS_AF 256
#define WS_E2 (256 + B_ * A_ * F_)

// ---- kernel 0: wv[i] = sum_f W[i,f] * (a[f] + a[f+F]) ------------------
__global__ __launch_bounds__(256) void wv_kernel(const float* __restrict__ W,
                                                 const float* __restrict__ a,
                                                 float* __restrict__ ws) {
    __shared__ float as_[F_];
    int t = threadIdx.x;
    as_[t] = a[t] + a[t + F_];
    __syncthreads();
    float acc = 0.f;
    const float* wrow = W + t * F_;
#pragma unroll 8
    for (int f = 0; f < F_; ++f) acc += wrow[f] * as_[f];
    ws[WS_WV + t] = acc;
}

// ---- kernel 1: anchor_feat[b,k,:] = fatoms[b, idx[b,k], :] @ W ; e2 ----
__global__ __launch_bounds__(256) void anchor_kernel(const float* __restrict__ fatoms,
                                                     const int* __restrict__ anchor_idx,
                                                     const float* __restrict__ W,
                                                     const float* __restrict__ a,
                                                     float* __restrict__ ws) {
    int bk = blockIdx.x;  // b*A_ + k
    int b  = bk / A_;
    int f  = threadIdx.x;
    __shared__ float xs[F_];
    __shared__ float red[F_];
    int idx = anchor_idx[bk];
    xs[f] = fatoms[((size_t)b * N_ + idx) * F_ + f];
    __syncthreads();
    float acc = 0.f;
#pragma unroll 8
    for (int i = 0; i < F_; ++i) acc += xs[i] * W[i * F_ + f];  // coalesced over f
    ws[WS_AF + bk * F_ + f] = acc;
    red[f] = acc * (a[f] - a[f + F_]);
    __syncthreads();
    for (int s = 128; s > 0; s >>= 1) {
        if (f < s) red[f] += red[f + s];
        __syncthreads();
    }
    if (f == 0) ws[WS_E2 + bk] = red[0];
}

// ---- kernel 2: main streaming kernel, one wave per row -----------------
#define RPW 16  // rows per wave
#define WPB 4   // waves per block

__global__ __launch_bounds__(256) void main_kernel(const float* __restrict__ fatoms,
                                                   const int* __restrict__ agraph,
                                                   const int* __restrict__ anchor_idx,
                                                   const float* __restrict__ ws,
                                                   float* __restrict__ out) {
    int tid  = threadIdx.x;
    int wave = tid >> 6, lane = tid & 63;
    const int rows_per_block   = WPB * RPW;            // 64
    const int blocks_per_batch = N_ / rows_per_block;  // 64
    int b     = blockIdx.x / blocks_per_batch;
    int chunk = blockIdx.x % blocks_per_batch;
    int row0  = chunk * rows_per_block + wave * RPW;

    const float* wv = ws + WS_WV;
    const float* af = ws + WS_AF + b * (A_ * F_);
    const float* e2 = ws + WS_E2 + b * A_;

    // per-wave constants: wv fragment, anchor_feat fragments, e2, anchor ids
    float4 wvr = *(const float4*)(wv + lane * 4);
    float4 afr[A_];
    float  e2r[A_];
    int    anch[A_];
#pragma unroll
    for (int k = 0; k < A_; ++k) {
        afr[k]  = *(const float4*)(af + k * F_ + lane * 4);
        e2r[k]  = e2[k];
        anch[k] = anchor_idx[b * A_ + k];
    }

    for (int r = 0; r < RPW; ++r) {
        int    n      = row0 + r;
        size_t rowoff = (size_t)b * N_ + n;

        // e1 = fatoms[row] . wv   (float4/lane, wave-reduce)
        float4 x = *(const float4*)(fatoms + rowoff * F_ + lane * 4);
        float  d = x.x * wvr.x + x.y * wvr.y + x.z * wvr.z + x.w * wvr.w;
#pragma unroll
        for (int off = 32; off > 0; off >>= 1) d += __shfl_xor(d, off);

        // mask: any of the 32 agraph entries equals anchor k
        int g = agraph[rowoff * M_ + (lane & (M_ - 1))];  // lanes 32..63 duplicate 0..31
        float ek[A_];
#pragma unroll
        for (int k = 0; k < A_; ++k)
            ek[k] = __any(g == anch[k]) ? (d + e2r[k]) : -1.0e9f;

        // softmax over A=8 (computed redundantly on all lanes; wave-uniform)
        float m = ek[0];
#pragma unroll
        for (int k = 1; k < A_; ++k) m = fmaxf(m, ek[k]);
        float s = 0.f, p[A_];
#pragma unroll
        for (int k = 0; k < A_; ++k) { p[k] = __expf(ek[k] - m); s += p[k]; }
        float inv = 1.f / s;

        // out[row] = sum_k attn_k * anchor_feat[b,k,:]
        float4 o = make_float4(0.f, 0.f, 0.f, 0.f);
#pragma unroll
        for (int k = 0; k < A_; ++k) {
            float w = p[k] * inv;
            o.x += w * afr[k].x;
            o.y += w * afr[k].y;
            o.z += w * afr[k].z;
            o.w += w * afr[k].w;
        }
        *(float4*)(out + rowoff * F_ + lane * 4) = o;
    }
}

extern "C" void kernel_launch(void* const* d_in, const int* in_sizes, int n_in,
                              void* d_out, int out_size, void* d_ws, size_t ws_size,
                              hipStream_t stream) {
    const float* fatoms     = (const float*)d_in[0];
    const int*   agraph     = (const int*)d_in[1];
    const int*   anchor_idx = (const int*)d_in[2];
    const float* W          = (const float*)d_in[3];
    const float* a          = (const float*)d_in[4];
    float*       out        = (float*)d_out;
    float*       ws         = (float*)d_ws;

    hipLaunchKernelGGL(wv_kernel, dim3(1), dim3(256), 0, stream, W, a, ws);
    hipLaunchKernelGGL(anchor_kernel, dim3(B_ * A_), dim3(256), 0, stream,
                       fatoms, anchor_idx, W, a, ws);
    hipLaunchKernelGGL(main_kernel, dim3(B_ * (N_ / (WPB * RPW))), dim3(256), 0, stream,
                       fatoms, agraph, anchor_idx, ws, out);
}